// Round 2
// 1459.676 us; speedup vs baseline: 1.1250x; 1.1250x over previous
//
#include <hip/hip_runtime.h>
#include <cstddef>

typedef unsigned short u16;
typedef unsigned int u32;

#define N 384
#define NELEM (N*N)        // 147456
#define NCH 128
#define NMAT 256
#define EPS 1e-5f

// Muon quintic coefficients
#define QA 3.4445f
#define QB (-4.7750f)
#define QC 2.0315f

typedef __attribute__((ext_vector_type(8))) short bf16x8;   // 8 bf16 = 4 VGPRs
typedef __attribute__((ext_vector_type(4))) float f32x4;

__device__ __forceinline__ float bf2f(u16 h){ union{u32 u; float f;} v; v.u=((u32)h)<<16; return v.f; }
__device__ __forceinline__ u16 f2bf(float x){
  union{float f;u32 u;} v; v.f=x;
  u32 r=(v.u + 0x7FFFu + ((v.u>>16)&1u))>>16;   // RNE
  return (u16)r;
}

__device__ __forceinline__ float wave_sum(float v){
#pragma unroll
  for(int o=32;o>0;o>>=1) v += __shfl_down(v,o,64);
  return v;
}

__device__ __forceinline__ const float* mat_src(const float* ir, const float* vi, int m){
  return (m < NCH) ? (ir + (size_t)m*NELEM) : (vi + (size_t)(m-NCH)*NELEM);
}

__global__ void k_zero(float* __restrict__ x, int n){
  int i = blockIdx.x*256 + threadIdx.x;
  if(i < n) x[i] = 0.f;
}

// partial Frobenius^2 of (M+eps): grid (CH, 16), atomicAdd into f[mloc]
__global__ __launch_bounds__(256)
void k_frob_part(const float* __restrict__ ir, const float* __restrict__ vi,
                 float* __restrict__ f, int m0){
  int mloc = blockIdx.x;
  const float4* s4 = (const float4*)mat_src(ir, vi, m0+mloc) + blockIdx.y*(NELEM/4/16);
  float s = 0.f;
  for(int i=threadIdx.x; i<NELEM/4/16; i+=256){
    float4 v = s4[i];
    float a=v.x+EPS, b=v.y+EPS, c=v.z+EPS, d=v.w+EPS;
    s += a*a + b*b + c*c + d*d;
  }
  __shared__ float sm[4];
  int lane=threadIdx.x&63, w=threadIdx.x>>6;
  s = wave_sum(s);
  if(lane==0) sm[w]=s;
  __syncthreads();
  if(threadIdx.x==0) atomicAdd(&f[mloc], sm[0]+sm[1]+sm[2]+sm[3]);
}

// X = bf16((M+eps) * rsqrt(f))   grid (144,1,CH)
__global__ __launch_bounds__(256)
void k_init(const float* __restrict__ ir, const float* __restrict__ vi,
            const float* __restrict__ f, u16* __restrict__ Xg, int m0){
  int mloc = blockIdx.z;
  const float4* src = (const float4*)mat_src(ir, vi, m0+mloc);
  float inv = rsqrtf(f[mloc]);
  ushort4* X4 = (ushort4*)(Xg + (size_t)mloc*NELEM);
  int i = blockIdx.x*256 + threadIdx.x;
  float4 v = src[i];
  ushort4 o;
  o.x=f2bf((v.x+EPS)*inv); o.y=f2bf((v.y+EPS)*inv);
  o.z=f2bf((v.z+EPS)*inv); o.w=f2bf((v.w+EPS)*inv);
  X4[i] = o;
}

// Y = X^T (bf16, LDS-tiled)  grid (6,6,CH)
__global__ __launch_bounds__(256)
void k_transp(const u16* __restrict__ Xg, u16* __restrict__ Yg){
  __shared__ u16 t[64][68];
  size_t mat = (size_t)blockIdx.z*NELEM;
  const u16* X = Xg + mat; u16* Y = Yg + mat;
  int bx = blockIdx.x*64, by = blockIdx.y*64;
  int c = (threadIdx.x&15)*4, r0 = threadIdx.x>>4;
#pragma unroll
  for(int s=0;s<4;s++){
    int r = r0 + s*16;
    ushort4 v = *(const ushort4*)&X[(size_t)(by+r)*N + bx + c];
    t[r][c]=v.x; t[r][c+1]=v.y; t[r][c+2]=v.z; t[r][c+3]=v.w;
  }
  __syncthreads();
#pragma unroll
  for(int s=0;s<4;s++){
    int r = r0 + s*16;
    ushort4 v;
    v.x=t[c+0][r]; v.y=t[c+1][r]; v.z=t[c+2][r]; v.w=t[c+3][r];
    *(ushort4*)&Y[(size_t)(bx+r)*N + by + c] = v;
  }
}

// NT GEMM: C = alpha*(P*Q^T) + beta*D, optional transposed store to Tg.
// sym=1: 6 upper-tri tiles/matrix, mirror into Tg(=Cg), skip mirror on diag.
// 1D grid (T*CH blocks), XCD-pinned: matrix m always on XCD m&7.
// K-loop: double-buffered LDS, 2-phase (stage next || compute current),
// ONE barrier per K-step -> global_load_lds latency hides under MFMA.
// LDS XOR swizzle on staging as before (source-column swizzled, linear dest).
// Epilogue: transposed mirror staged through LDS (reusing the 32KB K-loop
// buffers) so T-stores are contiguous 256B row segments (no partial lines).
__global__ __launch_bounds__(256)
void k_gemm(const u16* __restrict__ Pg, const u16* __restrict__ Qg,
            u16* __restrict__ Cg, u16* __restrict__ Tg,
            const u16* __restrict__ Dg, float alpha, float beta, int sym){
  // 32 KB: buf0 {A:0..4095, B:4096..8191}, buf1 {A:8192.., B:12288..}
  // epilogue overlay: u16 tile[128][128] (transposed, XOR-swizzled)
  __shared__ __align__(16) u16 lds[16384];
  int tid = threadIdx.x, lane = tid&63, w = tid>>6;

  int T = sym ? 6 : 9;
  int CH = gridDim.x / T;
  int m, t;
  if((CH & 7) == 0){
    int xcd = blockIdx.x & 7;
    int b2  = blockIdx.x >> 3;
    t = b2 % T;
    m = xcd + 8*(b2 / T);
  } else {
    m = blockIdx.x / T;
    t = blockIdx.x - m*T;
  }
  int i0, j0;
  if(sym){
    const int it[6]={0,0,0,1,1,2};
    const int jt[6]={0,1,2,1,2,2};
    i0=it[t]; j0=jt[t];
  } else {
    i0 = t/3; j0 = t - 3*i0;
  }
  size_t mat = (size_t)m*NELEM;
  const u16* P = Pg + mat + (size_t)(i0*128)*N;
  const u16* Q = Qg + mat + (size_t)(j0*128)*N;

  // staging: per wave 2 A + 2 B instrs; instr s covers rows (w*2+s)*16..+15.
  // source column swizzled: chunk qs = q0 ^ ((srow>>1)&3)
  int srow = lane>>2;                       // 0..15
  int q0   = lane&3;
  int scol = (q0 ^ ((srow>>1)&3)) * 8;      // u16 offset in 32-wide k slice
  const u16* gA0 = P + (size_t)((w*2+0)*16 + srow)*N + scol;
  const u16* gA1 = P + (size_t)((w*2+1)*16 + srow)*N + scol;
  const u16* gB0 = Q + (size_t)((w*2+0)*16 + srow)*N + scol;
  const u16* gB1 = Q + (size_t)((w*2+1)*16 + srow)*N + scol;
  int l0 = (w*2+0)*512 + lane*8;            // LDS u16 offset within A (or B) slab
  int l1 = (w*2+1)*512 + lane*8;

  f32x4 acc[4][4];
#pragma unroll
  for(int r=0;r<4;r++)
#pragma unroll
    for(int c=0;c<4;c++) acc[r][c] = (f32x4)0.f;

  int wm = (w&1)*64, wn = (w>>1)*64;
  int quad = lane>>4, ln = lane&15;
  // inverse swizzle for fragment reads: chunk = quad ^ ((row>>1)&3)
  int swz = (quad ^ ((ln>>1)&3)) * 8;

#define GLD(gp, loff) \
  __builtin_amdgcn_global_load_lds((const __attribute__((address_space(1))) void*)(gp), \
                                   (__attribute__((address_space(3))) void*)&lds[loff], 16, 0, 0)

  // prologue: stage k=0 into buf0
  GLD(gA0, l0); GLD(gA1, l1);
  GLD(gB0, 4096+l0); GLD(gB1, 4096+l1);
  __syncthreads();                          // vmcnt(0) drain + barrier

  int cur = 0;
  for(int k0=0;k0<N;k0+=32){
    if(k0+32 < N){                          // prefetch next K-slice into other buf
      int nb = (cur^1)*8192;
      GLD(gA0+k0+32, nb+l0);       GLD(gA1+k0+32, nb+l1);
      GLD(gB0+k0+32, nb+4096+l0);  GLD(gB1+k0+32, nb+4096+l1);
    }
    int cb = cur*8192;
    bf16x8 af[4], bv[4];
#pragma unroll
    for(int r=0;r<4;r++) af[r] = *(const bf16x8*)&lds[cb + (wm + r*16 + ln)*32 + swz];
#pragma unroll
    for(int c=0;c<4;c++) bv[c] = *(const bf16x8*)&lds[cb + 4096 + (wn + c*16 + ln)*32 + swz];
#pragma unroll
    for(int r=0;r<4;r++)
#pragma unroll
      for(int c=0;c<4;c++)
        acc[r][c] = __builtin_amdgcn_mfma_f32_16x16x32_bf16(af[r], bv[c], acc[r][c], 0, 0, 0);
    __syncthreads();                        // prefetch landed + all frag reads done
    cur ^= 1;
  }
#undef GLD

  // epilogue
  u16* C = Cg + mat;
  const u16* D = Dg ? Dg + mat : nullptr;
  bool do_t = (Tg != nullptr) && !(sym && (i0==j0));
  int rowb = i0*128 + wm, colb = j0*128 + wn;
#pragma unroll
  for(int r=0;r<4;r++){
#pragma unroll
    for(int c=0;c<4;c++){
      int row0 = rowb + r*16 + quad*4;
      int col  = colb + c*16 + ln;
      float v0 = alpha*acc[r][c].x;
      float v1 = alpha*acc[r][c].y;
      float v2 = alpha*acc[r][c].z;
      float v3 = alpha*acc[r][c].w;
      if(D){
        v0 += beta*bf2f(D[(size_t)(row0+0)*N + col]);
        v1 += beta*bf2f(D[(size_t)(row0+1)*N + col]);
        v2 += beta*bf2f(D[(size_t)(row0+2)*N + col]);
        v3 += beta*bf2f(D[(size_t)(row0+3)*N + col]);
      }
      u16 h0=f2bf(v0), h1=f2bf(v1), h2=f2bf(v2), h3=f2bf(v3);
      C[(size_t)(row0+0)*N + col] = h0;
      C[(size_t)(row0+1)*N + col] = h1;
      C[(size_t)(row0+2)*N + col] = h2;
      C[(size_t)(row0+3)*N + col] = h3;
      if(do_t){
        // transposed stage into LDS tile[col][row], XOR-swizzled
        int lcol  = wn + c*16 + ln;          // local col 0..127
        int lrow0 = wm + r*16 + quad*4;      // local row 0..124 (mult of 4)
        int idx = (lcol*128 + lrow0) ^ ((lcol&7)<<3);
        ushort4 pk; pk.x=h0; pk.y=h1; pk.z=h2; pk.w=h3;
        *(ushort4*)&lds[idx] = pk;
      }
    }
  }
  if(do_t){
    __syncthreads();
    u16* Tm = Tg + mat;
    int rbase = i0*128, cbase = j0*128;
#pragma unroll
    for(int it8=0; it8<8; ++it8){
      int idx  = it8*256 + tid;              // 0..2047
      int lcol = idx>>4;                     // 0..127
      int ch   = idx&15;                     // 8-elem chunk within row
      int li = (lcol*128 + ch*8) ^ ((lcol&7)<<3);
      bf16x8 v = *(const bf16x8*)&lds[li];
      *(bf16x8*)&Tm[(size_t)(cbase+lcol)*N + rbase + ch*8] = v;
    }
  }
}

// partial trace(X .* (M+eps)): grid (CH,16), atomicAdd into p[m0+mloc]
__global__ __launch_bounds__(256)
void k_trace_part(const u16* __restrict__ Xg, const float* __restrict__ ir,
                  const float* __restrict__ vi, float* __restrict__ p, int m0){
  int mloc = blockIdx.x;
  const float4*  s4 = (const float4*)mat_src(ir, vi, m0+mloc) + blockIdx.y*(NELEM/4/16);
  const ushort4* x4 = (const ushort4*)(Xg + (size_t)mloc*NELEM) + blockIdx.y*(NELEM/4/16);
  float s = 0.f;
  for(int i=threadIdx.x; i<NELEM/4/16; i+=256){
    float4 v = s4[i]; ushort4 x = x4[i];
    s += bf2f(x.x)*(v.x+EPS) + bf2f(x.y)*(v.y+EPS)
       + bf2f(x.z)*(v.z+EPS) + bf2f(x.w)*(v.w+EPS);
  }
  __shared__ float sm[4];
  int lane=threadIdx.x&63, w=threadIdx.x>>6;
  s = wave_sum(s);
  if(lane==0) sm[w]=s;
  __syncthreads();
  if(threadIdx.x==0) atomicAdd(&p[m0+mloc], sm[0]+sm[1]+sm[2]+sm[3]);
}

__global__ void k_weights(const float* __restrict__ p, float* __restrict__ w1, float* __restrict__ w2){
  int c = threadIdx.x;
  if(c < NCH){
    float a = p[c], b = p[c+NCH];
    float den = a + b + EPS;
    w1[c] = a/den;
    w2[c] = b/den;
  }
}

__global__ __launch_bounds__(256)
void k_combine(const float* __restrict__ ir, const float* __restrict__ vi,
               const float* __restrict__ w1, const float* __restrict__ w2,
               float* __restrict__ out){
  int i = blockIdx.x*256 + threadIdx.x;
  int c = i / (NELEM/4);
  float4 a = ((const float4*)ir)[i];
  float4 b = ((const float4*)vi)[i];
  float x1 = w1[c], x2 = w2[c];
  float4 o;
  o.x = x1*a.x + x2*b.x; o.y = x1*a.y + x2*b.y;
  o.z = x1*a.z + x2*b.z; o.w = x1*a.w + x2*b.w;
  ((float4*)out)[i] = o;
}

extern "C" void kernel_launch(void* const* d_in, const int* in_sizes, int n_in,
                              void* d_out, int out_size, void* d_ws, size_t ws_size,
                              hipStream_t stream){
  const float* ir = (const float*)d_in[0];
  const float* vi = (const float*)d_in[1];
  float* out = (float*)d_out;

  // 4 bf16 buffers of CH matrices + small fp32 tail
  int CH = NMAT;
  while(CH > 1 && (size_t)4*CH*NELEM*2 + 4096 > ws_size) CH >>= 1;

  u16* b[4];
  for(int i=0;i<4;i++) b[i] = (u16*)d_ws + (size_t)i*CH*NELEM;
  float* tail = (float*)((u16*)d_ws + (size_t)4*CH*NELEM);
  float* p  = tail;          // NMAT
  float* w1 = p + NMAT;      // NCH
  float* w2 = w1 + NCH;      // NCH
  float* f  = w2 + NCH;      // CH

  k_zero<<<1,256,0,stream>>>(p, NMAT);
  for(int m0=0; m0<NMAT; m0+=CH){
    k_zero<<<1,256,0,stream>>>(f, CH);
    k_frob_part<<<dim3(CH,16),256,0,stream>>>(ir, vi, f, m0);
    k_init<<<dim3(NELEM/4/256,1,CH),256,0,stream>>>(ir, vi, f, b[0], m0);
    k_transp<<<dim3(6,6,CH),256,0,stream>>>(b[0], b[1]);

    int X=0, Y=1, f1=2, f2=3;
    dim3 gs(6*CH), gf(9*CH);
    // 5 quintic iterations: G=X^T X (via NT(Y,Y)); E=QB*G+QC*G^2; X'=QA*X+X*E; Y'=X'^T
    for(int q=0;q<5;q++){
      k_gemm<<<gs,256,0,stream>>>(b[Y],  b[Y],  b[f1], b[f1], nullptr, 1.f, 0.f, 1);
      k_gemm<<<gs,256,0,stream>>>(b[f1], b[f1], b[f2], b[f2], b[f1],   QC,  QB,  1);
      k_gemm<<<gf,256,0,stream>>>(b[X],  b[f2], b[f1], b[Y],  b[X],    1.f, QA,  0);
      int t=X; X=f1; f1=t;
    }
    // 3 cubic polish: X' = 1.5X - 0.5*X*G
    for(int q=0;q<3;q++){
      k_gemm<<<gs,256,0,stream>>>(b[Y], b[Y],  b[f1], b[f1], nullptr, 1.f,   0.f, 1);
      k_gemm<<<gf,256,0,stream>>>(b[X], b[f1], b[f2], (q==2)?nullptr:b[Y], b[X], -0.5f, 1.5f, 0);
      int t=X; X=f2; f2=t;
    }
    k_trace_part<<<dim3(CH,16),256,0,stream>>>(b[X], ir, vi, p, m0);
  }
  k_weights<<<1,128,0,stream>>>(p, w1, w2);
  k_combine<<<(NCH*(NELEM/4))/256,256,0,stream>>>(ir, vi, w1, w2, out);
}

// Round 3
// 1400.606 us; speedup vs baseline: 1.1724x; 1.0422x over previous
//
#include <hip/hip_runtime.h>
#include <cstddef>

typedef unsigned short u16;
typedef unsigned int u32;

#define N 384
#define NELEM (N*N)        // 147456
#define NCH 128
#define NMAT 256
#define EPS 1e-5f

// Muon quintic coefficients
#define QA 3.4445f
#define QB (-4.7750f)
#define QC 2.0315f

typedef __attribute__((ext_vector_type(8))) short bf16x8;   // 8 bf16 = 4 VGPRs
typedef __attribute__((ext_vector_type(4))) float f32x4;

__device__ __forceinline__ float bf2f(u16 h){ union{u32 u; float f;} v; v.u=((u32)h)<<16; return v.f; }
__device__ __forceinline__ u16 f2bf(float x){
  union{float f;u32 u;} v; v.f=x;
  u32 r=(v.u + 0x7FFFu + ((v.u>>16)&1u))>>16;   // RNE
  return (u16)r;
}

__device__ __forceinline__ float wave_sum(float v){
#pragma unroll
  for(int o=32;o>0;o>>=1) v += __shfl_down(v,o,64);
  return v;
}

__device__ __forceinline__ const float* mat_src(const float* ir, const float* vi, int m){
  return (m < NCH) ? (ir + (size_t)m*NELEM) : (vi + (size_t)(m-NCH)*NELEM);
}

__global__ void k_zero(float* __restrict__ x, int n){
  int i = blockIdx.x*256 + threadIdx.x;
  if(i < n) x[i] = 0.f;
}

// partial Frobenius^2 of (M+eps): grid (CH, 16), atomicAdd into f[mloc]
__global__ __launch_bounds__(256)
void k_frob_part(const float* __restrict__ ir, const float* __restrict__ vi,
                 float* __restrict__ f, int m0){
  int mloc = blockIdx.x;
  const float4* s4 = (const float4*)mat_src(ir, vi, m0+mloc) + blockIdx.y*(NELEM/4/16);
  float s = 0.f;
  for(int i=threadIdx.x; i<NELEM/4/16; i+=256){
    float4 v = s4[i];
    float a=v.x+EPS, b=v.y+EPS, c=v.z+EPS, d=v.w+EPS;
    s += a*a + b*b + c*c + d*d;
  }
  __shared__ float sm[4];
  int lane=threadIdx.x&63, w=threadIdx.x>>6;
  s = wave_sum(s);
  if(lane==0) sm[w]=s;
  __syncthreads();
  if(threadIdx.x==0) atomicAdd(&f[mloc], sm[0]+sm[1]+sm[2]+sm[3]);
}

// Fused: X = bf16((M+eps)*rsqrt(f)), Y = X^T.  grid (6,6,CH).
// Replaces k_init + k_transp: saves re-reading X (74 MB) and a dispatch.
__global__ __launch_bounds__(256)
void k_init_t(const float* __restrict__ ir, const float* __restrict__ vi,
              const float* __restrict__ f, u16* __restrict__ Xg,
              u16* __restrict__ Yg, int m0){
  __shared__ u16 t[64][68];
  int mloc = blockIdx.z;
  const float* M = mat_src(ir, vi, m0+mloc);
  float inv = rsqrtf(f[mloc]);
  size_t mat = (size_t)mloc*NELEM;
  u16* X = Xg + mat; u16* Y = Yg + mat;
  int bx = blockIdx.x*64, by = blockIdx.y*64;
  int c = (threadIdx.x&15)*4, r0 = threadIdx.x>>4;
#pragma unroll
  for(int s=0;s<4;s++){
    int r = r0 + s*16;
    float4 v = *(const float4*)&M[(size_t)(by+r)*N + bx + c];
    u16 h0=f2bf((v.x+EPS)*inv), h1=f2bf((v.y+EPS)*inv);
    u16 h2=f2bf((v.z+EPS)*inv), h3=f2bf((v.w+EPS)*inv);
    ushort4 o; o.x=h0; o.y=h1; o.z=h2; o.w=h3;
    *(ushort4*)&X[(size_t)(by+r)*N + bx + c] = o;
    t[r][c]=h0; t[r][c+1]=h1; t[r][c+2]=h2; t[r][c+3]=h3;
  }
  __syncthreads();
#pragma unroll
  for(int s=0;s<4;s++){
    int r = r0 + s*16;
    ushort4 v;
    v.x=t[c+0][r]; v.y=t[c+1][r]; v.z=t[c+2][r]; v.w=t[c+3][r];
    *(ushort4*)&Y[(size_t)(bx+r)*N + by + c] = v;
  }
}

// NT GEMM: C = alpha*(P*Q^T) + beta*D, optional transposed store to Tg.
// sym=1: 6 upper-tri tiles/matrix, mirror into Tg(=Cg), skip mirror on diag.
// 1D grid (T*CH blocks), XCD-pinned: matrix m always on XCD m&7.
// K-loop: 3-deep LDS pipeline with COUNTED vmcnt (never drains to 0 in the
// main loop): per step, s_waitcnt vmcnt(4) [oldest buffer's 4 loads done,
// next buffer's 4 stay in flight] -> raw s_barrier -> sched_barrier(0)
// [pins stage-issue below the barrier: a hoisted global_load_lds would
// overwrite a buffer other waves are still reading] -> issue stage k+2 ->
// ds_read frags -> MFMA. vmcnt wait is BEFORE the barrier because fragment
// reads cross wave boundaries (each wave reads rows staged by other waves).
// Trace mode (p_part!=nullptr): X_final is only consumed by trace(X.*M) —
// skip the C store entirely and reduce alpha*PQ^T+beta*D against (M+eps).
__global__ __launch_bounds__(256)
void k_gemm(const u16* __restrict__ Pg, const u16* __restrict__ Qg,
            u16* __restrict__ Cg, u16* __restrict__ Tg,
            const u16* __restrict__ Dg, float alpha, float beta, int sym,
            const float* __restrict__ trir, const float* __restrict__ trvi,
            float* __restrict__ p_part, int m0g){
  // 48 KB: 3 stage buffers of 8192 u16 {A:+0 (4K u16), B:+4096}.
  // epilogue overlay (do_t): u16 tile[128][128] in first 32 KB.
  __shared__ __align__(16) u16 lds[24576];
  int tid = threadIdx.x, lane = tid&63, w = tid>>6;

  int T = sym ? 6 : 9;
  int CH = gridDim.x / T;
  int m, t;
  if((CH & 7) == 0){
    int xcd = blockIdx.x & 7;
    int b2  = blockIdx.x >> 3;
    t = b2 % T;
    m = xcd + 8*(b2 / T);
  } else {
    m = blockIdx.x / T;
    t = blockIdx.x - m*T;
  }
  int i0, j0;
  if(sym){
    const int it[6]={0,0,0,1,1,2};
    const int jt[6]={0,1,2,1,2,2};
    i0=it[t]; j0=jt[t];
  } else {
    i0 = t/3; j0 = t - 3*i0;
  }
  size_t mat = (size_t)m*NELEM;
  const u16* P = Pg + mat + (size_t)(i0*128)*N;
  const u16* Q = Qg + mat + (size_t)(j0*128)*N;

  // staging: per wave 2 A + 2 B instrs; instr s covers rows (w*2+s)*16..+15.
  // source column swizzled: chunk qs = q0 ^ ((srow>>1)&3)
  int srow = lane>>2;                       // 0..15
  int q0   = lane&3;
  int scol = (q0 ^ ((srow>>1)&3)) * 8;      // u16 offset in 32-wide k slice
  const u16* gA0 = P + (size_t)((w*2+0)*16 + srow)*N + scol;
  const u16* gA1 = P + (size_t)((w*2+1)*16 + srow)*N + scol;
  const u16* gB0 = Q + (size_t)((w*2+0)*16 + srow)*N + scol;
  const u16* gB1 = Q + (size_t)((w*2+1)*16 + srow)*N + scol;
  int l0 = (w*2+0)*512 + lane*8;            // LDS u16 offset within a slab
  int l1 = (w*2+1)*512 + lane*8;

  f32x4 acc[4][4];
#pragma unroll
  for(int r=0;r<4;r++)
#pragma unroll
    for(int c=0;c<4;c++) acc[r][c] = (f32x4)0.f;

  int wm = (w&1)*64, wn = (w>>1)*64;
  int quad = lane>>4, ln = lane&15;
  // inverse swizzle for fragment reads: chunk = quad ^ ((row>>1)&3)
  int swz = (quad ^ ((ln>>1)&3)) * 8;

#define GLD(gp, loff) \
  __builtin_amdgcn_global_load_lds((const __attribute__((address_space(1))) void*)(gp), \
                                   (__attribute__((address_space(3))) void*)&lds[loff], 16, 0, 0)
#define STAGE(step, buf) { \
    GLD(gA0 + (step)*32, (buf)*8192 + l0); \
    GLD(gA1 + (step)*32, (buf)*8192 + l1); \
    GLD(gB0 + (step)*32, (buf)*8192 + 4096 + l0); \
    GLD(gB1 + (step)*32, (buf)*8192 + 4096 + l1); }

  // prologue: buffers for steps 0,1 in flight (8 outstanding per wave)
  STAGE(0, 0); STAGE(1, 1);

  const int NSTEP = N/32;                   // 12
#pragma unroll
  for(int k=0;k<NSTEP;k++){
    if(k < NSTEP-1) asm volatile("s_waitcnt vmcnt(4)" ::: "memory");
    else            asm volatile("s_waitcnt vmcnt(0)" ::: "memory");
    __builtin_amdgcn_s_barrier();
    __builtin_amdgcn_sched_barrier(0);
    if(k+2 < NSTEP) STAGE(k+2, (k+2)%3);
    int cb = (k%3)*8192;
    bf16x8 af[4], bv[4];
#pragma unroll
    for(int r=0;r<4;r++) af[r] = *(const bf16x8*)&lds[cb + (wm + r*16 + ln)*32 + swz];
#pragma unroll
    for(int c=0;c<4;c++) bv[c] = *(const bf16x8*)&lds[cb + 4096 + (wn + c*16 + ln)*32 + swz];
#pragma unroll
    for(int r=0;r<4;r++)
#pragma unroll
      for(int c=0;c<4;c++)
        acc[r][c] = __builtin_amdgcn_mfma_f32_16x16x32_bf16(af[r], bv[c], acc[r][c], 0, 0, 0);
  }
#undef STAGE
#undef GLD
  __syncthreads();                          // all reads done; LDS reusable

  // epilogue
  u16* C = Cg + mat;
  const u16* D = Dg ? Dg + mat : nullptr;
  bool do_t = (Tg != nullptr) && !(sym && (i0==j0));
  u16* Tm = Tg ? Tg + mat : nullptr;
  bool do_tr = (p_part != nullptr);
  const float* Mf = do_tr ? mat_src(trir, trvi, m0g + m) : nullptr;
  float ts = 0.f;
  int rowb = i0*128 + wm, colb = j0*128 + wn;
#pragma unroll
  for(int r=0;r<4;r++){
#pragma unroll
    for(int c=0;c<4;c++){
      int row0 = rowb + r*16 + quad*4;
      int col  = colb + c*16 + ln;
      float v0 = alpha*acc[r][c].x;
      float v1 = alpha*acc[r][c].y;
      float v2 = alpha*acc[r][c].z;
      float v3 = alpha*acc[r][c].w;
      if(D){
        v0 += beta*bf2f(D[(size_t)(row0+0)*N + col]);
        v1 += beta*bf2f(D[(size_t)(row0+1)*N + col]);
        v2 += beta*bf2f(D[(size_t)(row0+2)*N + col]);
        v3 += beta*bf2f(D[(size_t)(row0+3)*N + col]);
      }
      if(do_tr){
        ts += v0*(Mf[(size_t)(row0+0)*N + col]+EPS)
            + v1*(Mf[(size_t)(row0+1)*N + col]+EPS)
            + v2*(Mf[(size_t)(row0+2)*N + col]+EPS)
            + v3*(Mf[(size_t)(row0+3)*N + col]+EPS);
      } else {
        u16 h0=f2bf(v0), h1=f2bf(v1), h2=f2bf(v2), h3=f2bf(v3);
        C[(size_t)(row0+0)*N + col] = h0;
        C[(size_t)(row0+1)*N + col] = h1;
        C[(size_t)(row0+2)*N + col] = h2;
        C[(size_t)(row0+3)*N + col] = h3;
        if(do_t){
          // transposed stage into LDS tile[col][row], XOR-swizzled
          int lcol  = wn + c*16 + ln;        // local col 0..127
          int lrow0 = wm + r*16 + quad*4;    // local row 0..124 (mult of 4)
          int idx = (lcol*128 + lrow0) ^ ((lcol&7)<<3);
          ushort4 pk; pk.x=h0; pk.y=h1; pk.z=h2; pk.w=h3;
          *(ushort4*)&lds[idx] = pk;
        }
      }
    }
  }
  if(do_tr){
    ts = wave_sum(ts);
    float* smf = (float*)lds;
    if(lane==0) smf[w] = ts;
    __syncthreads();
    if(tid==0) atomicAdd(&p_part[m0g + m], smf[0]+smf[1]+smf[2]+smf[3]);
  }
  if(do_t){
    __syncthreads();
    int rbase = i0*128, cbase = j0*128;
#pragma unroll
    for(int it8=0; it8<8; ++it8){
      int idx  = it8*256 + tid;              // 0..2047
      int lcol = idx>>4;                     // 0..127
      int ch   = idx&15;                     // 8-elem chunk within row
      int li = (lcol*128 + ch*8) ^ ((lcol&7)<<3);
      bf16x8 v = *(const bf16x8*)&lds[li];
      *(bf16x8*)&Tm[(size_t)(cbase+lcol)*N + rbase + ch*8] = v;
    }
  }
}

// combine with inline weights: w1=p[c]/(p[c]+p[c+128]+EPS)
__global__ __launch_bounds__(256)
void k_combine_w(const float* __restrict__ ir, const float* __restrict__ vi,
                 const float* __restrict__ p, float* __restrict__ out){
  int i = blockIdx.x*256 + threadIdx.x;
  int c = i / (NELEM/4);
  float pa = p[c], pb = p[c+NCH];
  float den = pa + pb + EPS;
  float x1 = pa/den, x2 = pb/den;
  float4 a = ((const float4*)ir)[i];
  float4 b = ((const float4*)vi)[i];
  float4 o;
  o.x = x1*a.x + x2*b.x; o.y = x1*a.y + x2*b.y;
  o.z = x1*a.z + x2*b.z; o.w = x1*a.w + x2*b.w;
  ((float4*)out)[i] = o;
}

extern "C" void kernel_launch(void* const* d_in, const int* in_sizes, int n_in,
                              void* d_out, int out_size, void* d_ws, size_t ws_size,
                              hipStream_t stream){
  const float* ir = (const float*)d_in[0];
  const float* vi = (const float*)d_in[1];
  float* out = (float*)d_out;

  // 4 bf16 buffers of CH matrices + small fp32 tail (p[NMAT] + f[CH] <= 2 KB)
  int CH = NMAT;
  while(CH > 1 && (size_t)4*CH*NELEM*2 + 4096 > ws_size) CH >>= 1;

  u16* b[4];
  for(int i=0;i<4;i++) b[i] = (u16*)d_ws + (size_t)i*CH*NELEM;
  float* tail = (float*)((u16*)d_ws + (size_t)4*CH*NELEM);
  float* p  = tail;          // NMAT (trace accumulators)
  float* f  = p + NMAT;      // CH   (frobenius accumulators)

  k_zero<<<2,256,0,stream>>>(p, NMAT + CH);
  for(int m0=0; m0<NMAT; m0+=CH){
    if(m0) k_zero<<<(CH+255)/256,256,0,stream>>>(f, CH);
    k_frob_part<<<dim3(CH,16),256,0,stream>>>(ir, vi, f, m0);
    k_init_t<<<dim3(6,6,CH),256,0,stream>>>(ir, vi, f, b[0], b[1], m0);

    int X=0, Y=1, f1=2, f2=3;
    dim3 gs(6*CH), gf(9*CH);
    // 5 quintic iterations: G=X^T X (via NT(Y,Y)); E=QB*G+QC*G^2; X'=QA*X+X*E; Y'=X'^T
    for(int q=0;q<5;q++){
      k_gemm<<<gs,256,0,stream>>>(b[Y],  b[Y],  b[f1], b[f1], nullptr, 1.f, 0.f, 1,
                                  nullptr, nullptr, nullptr, 0);
      k_gemm<<<gs,256,0,stream>>>(b[f1], b[f1], b[f2], b[f2], b[f1],   QC,  QB,  1,
                                  nullptr, nullptr, nullptr, 0);
      k_gemm<<<gf,256,0,stream>>>(b[X],  b[f2], b[f1], b[Y],  b[X],    1.f, QA,  0,
                                  nullptr, nullptr, nullptr, 0);
      int t=X; X=f1; f1=t;
    }
    // 3 cubic polish: X' = 1.5X - 0.5*X*G; final one fuses trace(X'.*(M+eps))
    for(int q=0;q<3;q++){
      k_gemm<<<gs,256,0,stream>>>(b[Y], b[Y],  b[f1], b[f1], nullptr, 1.f,   0.f, 1,
                                  nullptr, nullptr, nullptr, 0);
      if(q==2)
        k_gemm<<<gf,256,0,stream>>>(b[X], b[f1], b[f2], nullptr, b[X], -0.5f, 1.5f, 0,
                                    ir, vi, p, m0);
      else
        k_gemm<<<gf,256,0,stream>>>(b[X], b[f1], b[f2], b[Y], b[X], -0.5f, 1.5f, 0,
                                    nullptr, nullptr, nullptr, 0);
      int t=X; X=f2; f2=t;
    }
  }
  k_combine_w<<<(NCH*(NELEM/4))/256,256,0,stream>>>(ir, vi, p, out);
}